// Round 2
// baseline (325.516 us; speedup 1.0000x reference)
//
#include <hip/hip_runtime.h>
#include <cstdint>

// Shapes (fixed by reference): b=4,h=8 -> BH=32 heads; n=2048; nc=1024; d=K=512.
#define NC    1024
#define D     512
#define KTOT  512
#define MTOT  32768       // BH * NC
#define BK    64

typedef short  short8  __attribute__((ext_vector_type(8)));   // 8 x bf16
typedef float  floatx4 __attribute__((ext_vector_type(4)));

__device__ inline void gl2lds16(const void* gptr, void* lptr) {
  __builtin_amdgcn_global_load_lds(
      (const __attribute__((address_space(1))) void*)gptr,
      (__attribute__((address_space(3))) void*)lptr,
      16, 0, 0);
}

__device__ inline unsigned short f2bf_rne(float f) {
  union { float f; unsigned u; } x; x.f = f;
  unsigned r = x.u + 0x7fffu + ((x.u >> 16) & 1u);
  return (unsigned short)(r >> 16);
}

// Merged conversion: U32 (n4U float4s) then W (n4W float4s) in one launch.
__global__ __launch_bounds__(256) void cvt_f32_bf16_all(
    const float* __restrict__ srcU, unsigned short* __restrict__ dstU, int n4U,
    const float* __restrict__ srcW, unsigned short* __restrict__ dstW, int n4W) {
  int i = blockIdx.x * 256 + threadIdx.x;
  const float* src;
  unsigned short* dst;
  int idx;
  if (i < n4U) {
    src = srcU; dst = dstU; idx = i;
  } else {
    idx = i - n4U;
    if (idx >= n4W) return;
    src = srcW; dst = dstW;
  }
  float4 v = ((const float4*)src)[idx];
  ushort4 o;
  o.x = f2bf_rne(v.x); o.y = f2bf_rne(v.y);
  o.z = f2bf_rne(v.z); o.w = f2bf_rne(v.w);
  ((ushort4*)dst)[idx] = o;
}

// Fused kernel: per workgroup, A rows [r0, r0+128] (129 rows, extra row for the
// P2 shift), dout cols [n0, n0+64). Three acc groups:
//   P0[j]  = u_j . W0^T,  P1[j] = u_j . W1^T,  P2s[j] = u_{j+1} . W2^T
// (block-2 MFMAs read A fragments at row+1; extra staged row zeroed at head
//  boundaries). Epilogue transposes E/O through LDS for float4 global IO.
__global__ __launch_bounds__(256, 2) void fused_uncompress_gemm(
    const unsigned short* __restrict__ Ub,   // (32768, 512) bf16
    const unsigned short* __restrict__ Wb,   // (512, 1536) bf16, row-major
    const float* __restrict__ U32,           // (32768, 512) f32
    const float* __restrict__ LQ,            // (32, 2048, 512) f32
    const float* __restrict__ bias,          // (512) f32
    float* __restrict__ out)                 // (32, 2048, 512) f32
{
  // LDS: A = 129 rows x 64 bf16 (128 B/row), B = 192 rows x 64 bf16.
  // XOR-swizzled 16B chunks: slot s of row r holds global chunk (s ^ (r&7)).
  __shared__ __attribute__((aligned(16))) unsigned char smem[129*128 + 192*128];
  unsigned char* smemA = smem;
  unsigned char* smemB = smem + 129*128;

  // XCD-aware bijective swizzle: dispatch id d -> XCD d%8 (round-robin).
  // Put all 8 N-tiles of an M-tile on ONE XCD so the 131 KB A-tile is
  // fetched into a single L2. tileM = ((d>>6)<<3)|(d&7), tileN = (d>>3)&7.
  const int bid   = blockIdx.x;
  const int tileM = ((bid >> 6) << 3) | (bid & 7);
  const int tileN = (bid >> 3) & 7;
  const int r0 = tileM * 128;
  const int n0 = tileN * 64;
  const int tid  = threadIdx.x;
  const int wv   = tid >> 6;
  const int ln   = tid & 63;
  const int quad = ln >> 4;
  const int am   = ln & 15;

  floatx4 acc[2][12];
  #pragma unroll
  for (int rt = 0; rt < 2; ++rt)
    #pragma unroll
    for (int ct = 0; ct < 12; ++ct)
      acc[rt][ct] = floatx4{0.f, 0.f, 0.f, 0.f};

  const bool zeroExtra = (((r0 + 128) & (NC - 1)) == 0);  // head boundary

  for (int kc = 0; kc < KTOT / BK; ++kc) {
    const int k0 = kc * BK;

    // ---- stage A rows 0..127 (wave wv: rows [wv*32, wv*32+32), 4 instrs x 8 rows)
    #pragma unroll
    for (int i = 0; i < 4; ++i) {
      int row = wv * 32 + i * 8 + (ln >> 3);
      int s   = ln & 7;
      int kch = s ^ (row & 7);
      const unsigned short* g = Ub + (size_t)(r0 + row) * KTOT + k0 + kch * 8;
      gl2lds16(g, smemA + (wv * 32 + i * 8) * 128);   // wave-uniform LDS base
    }
    // ---- stage A row 128 (row&7==0 -> identity swizzle)
    if (wv == 0 && ln < 8) {
      if (zeroExtra) {
        *(float4*)(smemA + 128 * 128 + ln * 16) = make_float4(0.f, 0.f, 0.f, 0.f);
      } else {
        const unsigned short* g = Ub + (size_t)(r0 + 128) * KTOT + k0 + ln * 8;
        gl2lds16(g, smemA + 128 * 128);
      }
    }
    // ---- stage B: rho = beta*64 + nl, beta in 0..2, nl in 0..63
    #pragma unroll
    for (int i = 0; i < 6; ++i) {
      int rho = wv * 48 + i * 8 + (ln >> 3);
      int s   = ln & 7;
      int kch = s ^ (rho & 7);
      int beta = rho >> 6;
      int nl   = rho & 63;
      const unsigned short* g =
          Wb + (size_t)(n0 + nl) * 1536 + beta * 512 + k0 + kch * 8;
      gl2lds16(g, smemB + (wv * 48 + i * 8) * 128);
    }
    __syncthreads();   // drains vmcnt(0) (global_load_lds) + lgkmcnt

    // ---- compute: wave wv owns rows [wv*32, wv*32+32), all 192 acc cols
    #pragma unroll
    for (int ks = 0; ks < 2; ++ks) {
      short8 a0[2], a1[2];
      #pragma unroll
      for (int rt = 0; rt < 2; ++rt) {
        int row  = wv * 32 + rt * 16 + am;
        int sl   = (ks * 4 + quad) ^ (row & 7);
        a0[rt] = *(const short8*)(smemA + row * 128 + sl * 16);
        int row1 = row + 1;
        int sl1  = (ks * 4 + quad) ^ (row1 & 7);
        a1[rt] = *(const short8*)(smemA + row1 * 128 + sl1 * 16);
      }
      #pragma unroll
      for (int ct = 0; ct < 12; ++ct) {
        int beta = ct >> 2;
        int nl   = (ct & 3) * 16 + am;
        int rho  = beta * 64 + nl;
        int sl   = (ks * 4 + quad) ^ (nl & 7);
        short8 b = *(const short8*)(smemB + rho * 128 + sl * 16);
        #pragma unroll
        for (int rt = 0; rt < 2; ++rt) {
          acc[rt][ct] = __builtin_amdgcn_mfma_f32_16x16x32_bf16(
              (beta == 2) ? a1[rt] : a0[rt], b, acc[rt][ct], 0, 0, 0);
        }
      }
    }
    __syncthreads();   // protect LDS before next stage
  }
  // (last __syncthreads guarantees all waves done reading smem -> reuse below)

  // ---- epilogue: C/D map col=lane&15, row=quad*4+reg (verified m89/m91).
  // Stage E (=relu(P1+b)) and O (=relu(P0+P2+b)) through LDS per-wave
  // regions, then do ALL global IO as float4 (4 rows x 256B per store instr).
  // Per-wave region: E[16][68] + O[16][68] f32 (68-float row stride keeps
  // 16B alignment and staggers banks); 8704 B/wave, 34816 B total < 41 KB.
  const float inv3 = 1.0f / 3.0f;
  float* Ew = (float*)smem + (size_t)wv * 2 * 16 * 68;
  float* Ow = Ew + 16 * 68;

  #pragma unroll
  for (int rt = 0; rt < 2; ++rt) {
    // write phase: lane-local acc -> LDS [row16][col]
    #pragma unroll
    for (int dt = 0; dt < 4; ++dt) {
      float bv = bias[n0 + dt * 16 + am];
      #pragma unroll
      for (int r = 0; r < 4; ++r) {
        int row16 = quad * 4 + r;
        float p0 = acc[rt][dt][r];
        float p1 = acc[rt][4 + dt][r];
        float p2 = acc[rt][8 + dt][r];
        Ew[row16 * 68 + dt * 16 + am] = fmaxf(p1 + bv, 0.f);
        Ow[row16 * 68 + dt * 16 + am] = fmaxf(p0 + p2 + bv, 0.f);
      }
    }
    // read + global phase: lane (quad,am) handles row16 = rr*4+quad,
    // cols [4*am, 4*am+4) -> float4 everywhere.
    #pragma unroll
    for (int rr = 0; rr < 4; ++rr) {
      int row16 = rr * 4 + quad;
      int jl = wv * 32 + rt * 16 + row16;
      int j  = r0 + jl;
      int head = j >> 10;          // / NC
      int jn   = j & (NC - 1);
      float4 ev = *(const float4*)(Ew + row16 * 68 + am * 4);
      float4 ov = *(const float4*)(Ow + row16 * 68 + am * 4);
      size_t ucol = (size_t)j * D + n0 + am * 4;
      float4 u0 = *(const float4*)(U32 + ucol);
      float4 u1 = make_float4(0.f, 0.f, 0.f, 0.f);
      if (jn != NC - 1) u1 = *(const float4*)(U32 + ucol + D);
      size_t ob = ((size_t)head * 2048 + 2 * jn) * D + n0 + am * 4;
      float4 lq0 = *(const float4*)(LQ + ob);
      float4 lq1 = *(const float4*)(LQ + ob + D);
      float4 o0, o1;
      o0.x = lq0.x + ev.x + u0.x * inv3;
      o0.y = lq0.y + ev.y + u0.y * inv3;
      o0.z = lq0.z + ev.z + u0.z * inv3;
      o0.w = lq0.w + ev.w + u0.w * inv3;
      o1.x = lq1.x + ov.x + (u0.x + u1.x) * inv3;
      o1.y = lq1.y + ov.y + (u0.y + u1.y) * inv3;
      o1.z = lq1.z + ov.z + (u0.z + u1.z) * inv3;
      o1.w = lq1.w + ov.w + (u0.w + u1.w) * inv3;
      *(float4*)(out + ob)     = o0;
      *(float4*)(out + ob + D) = o1;
    }
    // rt=1 pass overwrites this wave's own LDS region only; same-wave
    // ds ordering (lgkmcnt) suffices, no cross-wave hazard -> no barrier.
  }
}

extern "C" void kernel_launch(void* const* d_in, const int* in_sizes, int n_in,
                              void* d_out, int out_size, void* d_ws, size_t ws_size,
                              hipStream_t stream) {
  const float* LQ   = (const float*)d_in[0];   // (4,8,2048,512)
  const float* U32  = (const float*)d_in[1];   // (4,8,1024,512)
  const float* W    = (const float*)d_in[2];   // (512, 1536)
  const float* bias = (const float*)d_in[3];   // (512)
  // d_in[4] = i (unused; dropout p=0)
  float* out = (float*)d_out;

  unsigned short* Ub = (unsigned short*)d_ws;                         // 33.5 MB
  unsigned short* Wb = (unsigned short*)((char*)d_ws + (size_t)MTOT * KTOT * 2);

  const int n4U = MTOT * KTOT / 4;     // 4,194,304
  const int n4W = 512 * 1536 / 4;      // 196,608
  cvt_f32_bf16_all<<<(n4U + n4W + 255) / 256, 256, 0, stream>>>(
      U32, Ub, n4U, W, Wb, n4W);

  // 2048 blocks = 256 M-tiles x 8 N-tiles, XCD-swizzled in-kernel.
  fused_uncompress_gemm<<<dim3(2048), dim3(256), 0, stream>>>(
      Ub, Wb, U32, LQ, bias, out);
}

// Round 3
// 320.957 us; speedup vs baseline: 1.0142x; 1.0142x over previous
//
#include <hip/hip_runtime.h>
#include <cstdint>

// Shapes (fixed by reference): b=4,h=8 -> BH=32 heads; n=2048; nc=1024; d=K=512.
#define NC    1024
#define D     512
#define KTOT  512
#define MTOT  32768       // BH * NC
#define BK    32          // K-step (halved for double-buffer in same LDS)
#define NKC   16          // KTOT / BK
// Per-buffer LDS: A 129 rows x 32 bf16 (64 B) + B 192 rows x 32 bf16 (64 B)
#define ABYTES (129 * 64)
#define BBYTES (192 * 64)
#define BUFB   (ABYTES + BBYTES)   // 20544

typedef short  short8  __attribute__((ext_vector_type(8)));   // 8 x bf16
typedef float  floatx4 __attribute__((ext_vector_type(4)));

__device__ inline void gl2lds16(const void* gptr, void* lptr) {
  __builtin_amdgcn_global_load_lds(
      (const __attribute__((address_space(1))) void*)gptr,
      (__attribute__((address_space(3))) void*)lptr,
      16, 0, 0);
}

__device__ inline unsigned short f2bf_rne(float f) {
  union { float f; unsigned u; } x; x.f = f;
  unsigned r = x.u + 0x7fffu + ((x.u >> 16) & 1u);
  return (unsigned short)(r >> 16);
}

// Merged conversion: U32 (n4U float4s) then W (n4W float4s) in one launch.
__global__ __launch_bounds__(256) void cvt_f32_bf16_all(
    const float* __restrict__ srcU, unsigned short* __restrict__ dstU, int n4U,
    const float* __restrict__ srcW, unsigned short* __restrict__ dstW, int n4W) {
  int i = blockIdx.x * 256 + threadIdx.x;
  const float* src;
  unsigned short* dst;
  int idx;
  if (i < n4U) {
    src = srcU; dst = dstU; idx = i;
  } else {
    idx = i - n4U;
    if (idx >= n4W) return;
    src = srcW; dst = dstW;
  }
  float4 v = ((const float4*)src)[idx];
  ushort4 o;
  o.x = f2bf_rne(v.x); o.y = f2bf_rne(v.y);
  o.z = f2bf_rne(v.z); o.w = f2bf_rne(v.w);
  ((ushort4*)dst)[idx] = o;
}

// Fused kernel: per workgroup, A rows [r0, r0+128] (129 rows, extra row for the
// P2 shift), dout cols [n0, n0+64). Three acc groups:
//   P0[j]  = u_j . W0^T,  P1[j] = u_j . W1^T,  P2s[j] = u_{j+1} . W2^T
// 2-phase schedule (T3-min): stage K-tile kc+1 into buf^1 BEFORE computing
// kc from buf; __syncthreads() at iteration end = vmcnt(0)+barrier, so the
// stage latency hides under the 24-MFMA compute phase.
// XOR swizzle (BK=32): slot s of row r holds global 16B chunk (s ^ (r&3)).
__global__ __launch_bounds__(256, 2) void fused_uncompress_gemm(
    const unsigned short* __restrict__ Ub,   // (32768, 512) bf16
    const unsigned short* __restrict__ Wb,   // (512, 1536) bf16, row-major
    const float* __restrict__ U32,           // (32768, 512) f32
    const float* __restrict__ LQ,            // (32, 2048, 512) f32
    const float* __restrict__ bias,          // (512) f32
    float* __restrict__ out)                 // (32, 2048, 512) f32
{
  __shared__ __attribute__((aligned(16))) unsigned char smem[2 * BUFB];

  // XCD-aware bijective swizzle (2048 % 8 == 0): all 8 N-tiles of an M-tile
  // land on one XCD so the A-tile is fetched into a single L2.
  const int bid   = blockIdx.x;
  const int tileM = ((bid >> 6) << 3) | (bid & 7);
  const int tileN = (bid >> 3) & 7;
  const int r0 = tileM * 128;
  const int n0 = tileN * 64;
  const int tid  = threadIdx.x;
  const int wv   = tid >> 6;
  const int ln   = tid & 63;
  const int quad = ln >> 4;
  const int am   = ln & 15;

  floatx4 acc[2][12];
  #pragma unroll
  for (int rt = 0; rt < 2; ++rt)
    #pragma unroll
    for (int ct = 0; ct < 12; ++ct)
      acc[rt][ct] = floatx4{0.f, 0.f, 0.f, 0.f};

  const bool zeroExtra = (((r0 + 128) & (NC - 1)) == 0);  // head boundary

  // ---- staging of one BK=32 K-tile into buffer `buf` (all gload_lds issue)
  auto stage = [&](int buf, int kc) {
    unsigned char* sA = smem + buf * BUFB;
    unsigned char* sB = sA + ABYTES;
    const int k0 = kc * BK;
    // A rows 0..127: 16 rows per instr (lane ln -> row ln>>2, slot ln&3)
    #pragma unroll
    for (int i = 0; i < 2; ++i) {
      int row = wv * 32 + i * 16 + (ln >> 2);
      int kch = (ln & 3) ^ (row & 3);
      const unsigned short* g = Ub + (size_t)(r0 + row) * KTOT + k0 + kch * 8;
      gl2lds16(g, sA + (wv * 32 + i * 16) * 64);   // wave-uniform LDS base
    }
    // A row 128 (row&3==0 -> identity swizzle); zeroExtra handled pre-loop
    if (!zeroExtra && wv == 0 && ln < 4) {
      const unsigned short* g = Ub + (size_t)(r0 + 128) * KTOT + k0 + ln * 8;
      gl2lds16(g, sA + 128 * 64);
    }
    // B: rho = beta*64 + nl, beta in 0..2, nl in 0..63
    #pragma unroll
    for (int i = 0; i < 3; ++i) {
      int rho = wv * 48 + i * 16 + (ln >> 2);
      int kch = (ln & 3) ^ (rho & 3);
      int beta = rho >> 6;
      int nl   = rho & 63;
      const unsigned short* g =
          Wb + (size_t)(n0 + nl) * 1536 + beta * 512 + k0 + kch * 8;
      gl2lds16(g, sB + (wv * 48 + i * 16) * 64);
    }
  };

  // ---- prologue: zero the extra row in BOTH buffers (never re-staged),
  // stage kc=0 into buffer 0, then one exposed drain.
  if (zeroExtra && wv == 0 && ln < 4) {
    *(float4*)(smem + ABYTES - 64 + ln * 16)        = make_float4(0.f, 0.f, 0.f, 0.f);
    *(float4*)(smem + BUFB + ABYTES - 64 + ln * 16) = make_float4(0.f, 0.f, 0.f, 0.f);
  }
  stage(0, 0);
  __syncthreads();

  #pragma unroll 2
  for (int kc = 0; kc < NKC; ++kc) {
    const int cur = kc & 1;
    if (kc < NKC - 1) stage(cur ^ 1, kc + 1);   // issue next tile FIRST

    unsigned char* sA = smem + cur * BUFB;
    unsigned char* sB = sA + ABYTES;
    short8 a0[2], a1[2];
    #pragma unroll
    for (int rt = 0; rt < 2; ++rt) {
      int row  = wv * 32 + rt * 16 + am;
      int sl   = quad ^ (row & 3);
      a0[rt] = *(const short8*)(sA + row * 64 + sl * 16);
      int row1 = row + 1;
      int sl1  = quad ^ (row1 & 3);
      a1[rt] = *(const short8*)(sA + row1 * 64 + sl1 * 16);
    }
    #pragma unroll
    for (int ct = 0; ct < 12; ++ct) {
      int beta = ct >> 2;
      int nl   = (ct & 3) * 16 + am;
      int rho  = beta * 64 + nl;
      int sl   = quad ^ (rho & 3);
      short8 b = *(const short8*)(sB + rho * 64 + sl * 16);
      #pragma unroll
      for (int rt = 0; rt < 2; ++rt) {
        acc[rt][ct] = __builtin_amdgcn_mfma_f32_16x16x32_bf16(
            (beta == 2) ? a1[rt] : a0[rt], b, acc[rt][ct], 0, 0, 0);
      }
    }
    __syncthreads();   // vmcnt(0)+barrier: next tile landed, LDS safe to swap
  }

  // ---- epilogue: C/D map col=lane&15, row=quad*4+reg (verified m89/m91).
  // Stage E (=relu(P1+b)) and O (=relu(P0+P2+b)) through LDS per-wave
  // regions, then do ALL global IO as float4. Per-wave: E[16][68]+O[16][68]
  // f32 = 8704 B/wave, 34816 B total < 41088 B.
  const float inv3 = 1.0f / 3.0f;
  float* Ew = (float*)smem + (size_t)wv * 2 * 16 * 68;
  float* Ow = Ew + 16 * 68;

  #pragma unroll
  for (int rt = 0; rt < 2; ++rt) {
    // write phase: lane-local acc -> LDS [row16][col]
    #pragma unroll
    for (int dt = 0; dt < 4; ++dt) {
      float bv = bias[n0 + dt * 16 + am];
      #pragma unroll
      for (int r = 0; r < 4; ++r) {
        int row16 = quad * 4 + r;
        float p0 = acc[rt][dt][r];
        float p1 = acc[rt][4 + dt][r];
        float p2 = acc[rt][8 + dt][r];
        Ew[row16 * 68 + dt * 16 + am] = fmaxf(p1 + bv, 0.f);
        Ow[row16 * 68 + dt * 16 + am] = fmaxf(p0 + p2 + bv, 0.f);
      }
    }
    // read + global phase: lane (quad,am) handles row16 = rr*4+quad,
    // cols [4*am, 4*am+4) -> float4 everywhere.
    #pragma unroll
    for (int rr = 0; rr < 4; ++rr) {
      int row16 = rr * 4 + quad;
      int jl = wv * 32 + rt * 16 + row16;
      int j  = r0 + jl;
      int head = j >> 10;          // / NC
      int jn   = j & (NC - 1);
      float4 ev = *(const float4*)(Ew + row16 * 68 + am * 4);
      float4 ov = *(const float4*)(Ow + row16 * 68 + am * 4);
      size_t ucol = (size_t)j * D + n0 + am * 4;
      float4 u0 = *(const float4*)(U32 + ucol);
      float4 u1 = make_float4(0.f, 0.f, 0.f, 0.f);
      if (jn != NC - 1) u1 = *(const float4*)(U32 + ucol + D);
      size_t ob = ((size_t)head * 2048 + 2 * jn) * D + n0 + am * 4;
      float4 lq0 = *(const float4*)(LQ + ob);
      float4 lq1 = *(const float4*)(LQ + ob + D);
      float4 o0, o1;
      o0.x = lq0.x + ev.x + u0.x * inv3;
      o0.y = lq0.y + ev.y + u0.y * inv3;
      o0.z = lq0.z + ev.z + u0.z * inv3;
      o0.w = lq0.w + ev.w + u0.w * inv3;
      o1.x = lq1.x + ov.x + (u0.x + u1.x) * inv3;
      o1.y = lq1.y + ov.y + (u0.y + u1.y) * inv3;
      o1.z = lq1.z + ov.z + (u0.z + u1.z) * inv3;
      o1.w = lq1.w + ov.w + (u0.w + u1.w) * inv3;
      *(float4*)(out + ob)     = o0;
      *(float4*)(out + ob + D) = o1;
    }
    // rt=1 pass overwrites this wave's own LDS region only; same-wave
    // ds ordering (lgkmcnt) suffices, no cross-wave hazard -> no barrier.
  }
}

extern "C" void kernel_launch(void* const* d_in, const int* in_sizes, int n_in,
                              void* d_out, int out_size, void* d_ws, size_t ws_size,
                              hipStream_t stream) {
  const float* LQ   = (const float*)d_in[0];   // (4,8,2048,512)
  const float* U32  = (const float*)d_in[1];   // (4,8,1024,512)
  const float* W    = (const float*)d_in[2];   // (512, 1536)
  const float* bias = (const float*)d_in[3];   // (512)
  // d_in[4] = i (unused; dropout p=0)
  float* out = (float*)d_out;

  unsigned short* Ub = (unsigned short*)d_ws;                         // 33.5 MB
  unsigned short* Wb = (unsigned short*)((char*)d_ws + (size_t)MTOT * KTOT * 2);

  const int n4U = MTOT * KTOT / 4;     // 4,194,304
  const int n4W = 512 * 1536 / 4;      // 196,608
  cvt_f32_bf16_all<<<(n4U + n4W + 255) / 256, 256, 0, stream>>>(
      U32, Ub, n4U, W, Wb, n4W);

  // 2048 blocks = 256 M-tiles x 8 N-tiles, XCD-swizzled in-kernel.
  fused_uncompress_gemm<<<dim3(2048), dim3(256), 0, stream>>>(
      Ub, Wb, U32, LQ, bias, out);
}